// Round 4
// baseline (1670.905 us; speedup 1.0000x reference)
//
#include <hip/hip_runtime.h>

#define N_NODES 100000
#define N_EDGES 1600000
#define N_GRAPHS 128
#define FDIM 64
#define EPSV 1e-5f
#define NEG 0.01f

#define NB 782              // ceil(N_NODES/128) dst-range buckets
#define PART_BLOCKS 391     // ceil(N_EDGES/4096)

__device__ __forceinline__ float leaky(float x){ return x >= 0.f ? x : NEG*x; }
__device__ __forceinline__ float bcastf(float v, int k){
    return __uint_as_float((unsigned)__builtin_amdgcn_readlane(__float_as_uint(v), k));
}

// ================= bucket histogram (782 bins, LDS-reduced) =================
__global__ __launch_bounds__(256) void k_bh(const int* __restrict__ dst, int* __restrict__ bhist){
    __shared__ int lh[NB];
    int t = threadIdx.x;
    for (int i = t; i < NB; i += 256) lh[i] = 0;
    __syncthreads();
    int base = blockIdx.x * 4096;
    #pragma unroll
    for (int k = 0; k < 16; ++k){
        int e = base + k*256 + t;
        if (e < N_EDGES) atomicAdd(&lh[dst[e] >> 7], 1);
    }
    __syncthreads();
    for (int i = t; i < NB; i += 256) if (lh[i]) atomicAdd(&bhist[i], lh[i]);
}

// ================= single-block exclusive scan of NB bucket sizes =================
__global__ __launch_bounds__(256) void k_bscan(const int* __restrict__ bhist,
                                               int* __restrict__ boff, int* __restrict__ cur){
    __shared__ int lds[256];
    int t = threadIdx.x;
    int base = t*4;
    int v0 = (base+0 < NB) ? bhist[base+0] : 0;
    int v1 = (base+1 < NB) ? bhist[base+1] : 0;
    int v2 = (base+2 < NB) ? bhist[base+2] : 0;
    int v3 = (base+3 < NB) ? bhist[base+3] : 0;
    lds[t] = v0+v1+v2+v3; __syncthreads();
    for (int off = 1; off < 256; off <<= 1){
        int add = (t >= off) ? lds[t-off] : 0; __syncthreads();
        lds[t] += add; __syncthreads();
    }
    int excl = (t > 0) ? lds[t-1] : 0;
    int p0 = excl, p1 = excl+v0, p2 = excl+v0+v1, p3 = excl+v0+v1+v2;
    if (base+0 < NB){ boff[base+0] = p0; cur[base+0] = p0; }
    if (base+1 < NB){ boff[base+1] = p1; cur[base+1] = p1; }
    if (base+2 < NB){ boff[base+2] = p2; cur[base+2] = p2; }
    if (base+3 < NB){ boff[base+3] = p3; cur[base+3] = p3; }
    if (t == 0) boff[NB] = N_EDGES;
}

// ================= partition edges into dst buckets, packed (src<<7)|dst_local =================
__global__ __launch_bounds__(256) void k_part(const int* __restrict__ src, const int* __restrict__ dst,
                                              int* __restrict__ cur, int* __restrict__ packed){
    __shared__ int lh[NB];
    __shared__ int lc[NB];
    int t = threadIdx.x;
    for (int i = t; i < NB; i += 256) lh[i] = 0;
    __syncthreads();
    int base = blockIdx.x * 4096;
    int d[16];
    #pragma unroll
    for (int k = 0; k < 16; ++k){
        int e = base + k*256 + t;
        d[k] = (e < N_EDGES) ? dst[e] : -1;
        if (d[k] >= 0) atomicAdd(&lh[d[k] >> 7], 1);
    }
    __syncthreads();
    for (int i = t; i < NB; i += 256) lc[i] = atomicAdd(&cur[i], lh[i]);
    __syncthreads();
    #pragma unroll
    for (int k = 0; k < 16; ++k){
        int e = base + k*256 + t;
        if (e < N_EDGES){
            int b = d[k] >> 7;
            int p = atomicAdd(&lc[b], 1);
            packed[p] = (src[e] << 7) | (d[k] & 127);
        }
    }
}

// ============ bucket aggregation: LDS accumulate + mean (+deg store) ============
template<bool WDEG>
__global__ __launch_bounds__(256) void k_bagg(
    const float* __restrict__ xin, const int* __restrict__ packed,
    const int* __restrict__ boff, float* __restrict__ agg, float* __restrict__ deg)
{
    __shared__ float acc[128*65];   // +1 dword row pad: spreads dl across banks
    __shared__ float scnt[128];
    int t = threadIdx.x;
    for (int i = t; i < 128*65; i += 256) acc[i] = 0.f;
    if (t < 128) scnt[t] = 0.f;
    __syncthreads();
    int b = blockIdx.x;
    int e0 = boff[b], e1 = boff[b+1];
    int lane = t & 63, wave = t >> 6, sub = lane >> 4, q = lane & 15;
    for (int e = e0 + (wave<<2) + sub; e < e1; e += 16){
        int v = packed[e];
        int srcn = ((unsigned)v) >> 7;
        int dl = v & 127;
        const float4* row = (const float4*)(xin + ((size_t)srcn << 6));
        float4 x4 = row[q];
        float* a = &acc[dl*65 + (q<<2)];
        atomicAdd(a+0, x4.x); atomicAdd(a+1, x4.y);
        atomicAdd(a+2, x4.z); atomicAdd(a+3, x4.w);
        if (q == 0) atomicAdd(&scnt[dl], 1.f);
    }
    __syncthreads();
    int nbase = b << 7;
    int nloc = min(128, N_NODES - nbase);
    for (int i = t; i < (nloc<<6); i += 256){
        int nl = i >> 6, j = i & 63;
        float rd = 1.f / fmaxf(scnt[nl], 1.f);
        agg[((size_t)(nbase+nl) << 6) + j] = acc[nl*65 + j] * rd;
    }
    if (WDEG) for (int i = t; i < nloc; i += 256) deg[nbase+i] = scnt[i];
}

// ============ streaming dual-GEMM + leaky + BN partials; affine folded into weights ============
template<bool AFF>
__global__ __launch_bounds__(256) void k_gemm(
    float* aggh, const float* __restrict__ xin,
    const float* __restrict__ deg,
    const float* __restrict__ Wl, const float* __restrict__ bl,
    const float* __restrict__ Wr,
    const float* __restrict__ scale, const float* __restrict__ shift,
    float* __restrict__ bnsum, float* __restrict__ bnsq)
{
    __shared__ float sWl[4096];
    __shared__ float sWr[4096];
    __shared__ float red[256];
    int t = threadIdx.x;
    int lane = t & 63;
    for (int i = t; i < 4096; i += 256){
        float s = AFF ? scale[i >> 6] : 1.f;
        sWl[i] = Wl[i] * s;
        sWr[i] = Wr[i] * s;
    }
    float bb = bl[lane], bd = 0.f;
    if (AFF){
        #pragma unroll 8
        for (int k = 0; k < 64; ++k){
            float sh = shift[k];
            bb += sh * Wr[(k<<6) + lane];
            bd += sh * Wl[(k<<6) + lane];
        }
    }
    __syncthreads();
    float bs = 0.f, bq = 0.f;
    int wid = (blockIdx.x << 2) + (t >> 6);
    int nw = gridDim.x << 2;
    for (int c = wid; c < N_NODES/4; c += nw){
        int n0 = c << 2;
        float aA[4], aX[4], acc[4];
        #pragma unroll
        for (int m = 0; m < 4; ++m){
            aA[m] = aggh[((size_t)(n0+m) << 6) + lane];
            aX[m] = xin[((size_t)(n0+m) << 6) + lane];
            if (AFF) acc[m] = bb + (deg[n0+m] > 0.f ? bd : 0.f);
            else     acc[m] = bb;
        }
        #pragma unroll 8
        for (int k = 0; k < 64; ++k){
            float wl = sWl[(k<<6) + lane];
            float wr = sWr[(k<<6) + lane];
            #pragma unroll
            for (int m = 0; m < 4; ++m)
                acc[m] += bcastf(aA[m], k)*wl + bcastf(aX[m], k)*wr;
        }
        #pragma unroll
        for (int m = 0; m < 4; ++m){
            float h = leaky(acc[m]);
            aggh[((size_t)(n0+m) << 6) + lane] = h;
            bs += h; bq += h*h;
        }
    }
    red[t] = bs; __syncthreads();
    if (t < 64) atomicAdd(&bnsum[t], red[t]+red[t+64]+red[t+128]+red[t+192]);
    __syncthreads();
    red[t] = bq; __syncthreads();
    if (t < 64) atomicAdd(&bnsq[t],  red[t]+red[t+64]+red[t+128]+red[t+192]);
}

// ============ BN finalize ============
__global__ void k_bnfin(const float* __restrict__ sum, const float* __restrict__ sumsq,
                        const float* __restrict__ gamma, const float* __restrict__ beta,
                        float* __restrict__ scale, float* __restrict__ shift){
    int j = threadIdx.x;
    if (j < FDIM){
        float mu  = sum[j]   * (1.0f/N_NODES);
        float var = sumsq[j] * (1.0f/N_NODES) - mu*mu;
        float sc  = gamma[j] * rsqrtf(var + EPSV);
        scale[j] = sc;
        shift[j] = beta[j] - mu*sc;
    }
}

// ============ pooling: sorted batch -> segmented reduction ============
__global__ __launch_bounds__(256) void k_pool2(
    const float* __restrict__ h, const int* __restrict__ batch,
    const float* __restrict__ scale, const float* __restrict__ shift,
    float* __restrict__ pooled)
{
    __shared__ int seg[2];
    __shared__ float red[256];
    int g = blockIdx.x, t = threadIdx.x, j = t & 63, slot = t >> 6;
    if (t < 2){
        int target = g + t;
        int lo = 0, hi = N_NODES;
        while (lo < hi){ int mid = (lo+hi)>>1; if (batch[mid] < target) lo = mid+1; else hi = mid; }
        seg[t] = lo;
    }
    __syncthreads();
    int start = seg[0], end = seg[1];
    float acc = 0.f;
    for (int n = start + slot; n < end; n += 4)
        acc += h[(long long)n*FDIM + j];
    red[t] = acc; __syncthreads();
    if (t < 64){
        float s = red[t]+red[t+64]+red[t+128]+red[t+192];
        float c = fmaxf((float)(end - start), 1.f);
        pooled[g*FDIM + t] = (end > start) ? (s/c)*scale[t] + shift[t] : 0.f;
    }
}

// ============ final MLP ============
__global__ __launch_bounds__(256) void k_mlp(
    const float* __restrict__ pooled, const float* __restrict__ gf,
    const float* __restrict__ Wm0, const float* __restrict__ bm0,
    const float* __restrict__ Wm1, const float* __restrict__ bm1,
    const float* __restrict__ Wm2, const float* __restrict__ bm2,
    float* __restrict__ out)
{
    __shared__ float z[128];
    __shared__ float h1[256];
    __shared__ float h2[128];
    int g = blockIdx.x, t = threadIdx.x;
    if (t < 64)       z[t] = pooled[g*FDIM + t];
    else if (t < 128) z[t] = gf[g*FDIM + (t-64)];
    __syncthreads();
    float acc = bm0[t];
    #pragma unroll 8
    for (int k = 0; k < 128; ++k) acc += z[k]*Wm0[k*256 + t];
    h1[t] = leaky(acc);
    __syncthreads();
    if (t < 128){
        float a = bm1[t];
        #pragma unroll 8
        for (int k = 0; k < 256; ++k) a += h1[k]*Wm1[k*128 + t];
        h2[t] = leaky(a);
    }
    __syncthreads();
    if (t < 2){
        float a = bm2[t];
        for (int k = 0; k < 128; ++k) a += h2[k]*Wm2[k*2 + t];
        out[g*2 + t] = a;
    }
}

extern "C" void kernel_launch(void* const* d_in, const int* in_sizes, int n_in,
                              void* d_out, int out_size, void* d_ws, size_t ws_size,
                              hipStream_t stream) {
    const float* x     = (const float*)d_in[0];
    const int*   ei    = (const int*)d_in[1];
    const float* gf    = (const float*)d_in[2];
    const int*   batch = (const int*)d_in[3];
    const float* Wl0 = (const float*)d_in[4];
    const float* bl0 = (const float*)d_in[5];
    const float* Wr0 = (const float*)d_in[6];
    const float* g0  = (const float*)d_in[7];
    const float* b0  = (const float*)d_in[8];
    const float* Wl1 = (const float*)d_in[9];
    const float* bl1 = (const float*)d_in[10];
    const float* Wr1 = (const float*)d_in[11];
    const float* g1  = (const float*)d_in[12];
    const float* b1  = (const float*)d_in[13];
    const float* Wm0 = (const float*)d_in[14];
    const float* bm0 = (const float*)d_in[15];
    const float* Wm1 = (const float*)d_in[16];
    const float* bm1 = (const float*)d_in[17];
    const float* Wm2 = (const float*)d_in[18];
    const float* bm2 = (const float*)d_in[19];

    // ---- workspace (16B-aligned float region) ----
    int*   bhist  = (int*)d_ws;                      // [NB]
    int*   boff   = bhist + NB;                      // [NB+1]
    int*   cur    = boff + NB + 1;                   // [NB]  (+1 pad int => 2348 total)
    int*   packed = (int*)d_ws + 2348;               // [E]
    float* deg    = (float*)(packed + N_EDGES);      // [N]
    float* bufA   = deg + N_NODES;                   // [N,64] agg1 -> h1 (in-place)
    float* bufB   = bufA + (size_t)N_NODES*FDIM;     // [N,64] agg2 -> h2 (in-place)
    float* bnsum  = bufB + (size_t)N_NODES*FDIM;     // [64]
    float* bnsq   = bnsum + 64;
    float* scale0 = bnsum + 128;
    float* shift0 = bnsum + 192;
    float* scale1 = bnsum + 256;
    float* shift1 = bnsum + 320;
    float* pooled = bnsum + 384;                     // [128,64]

    const int* srcp = ei;
    const int* dstp = ei + N_EDGES;

    // ---- bucket partition build (replaces CSR hist/scan/fill) ----
    hipMemsetAsync(bhist, 0, NB*sizeof(int), stream);
    k_bh<<<PART_BLOCKS, 256, 0, stream>>>(dstp, bhist);
    k_bscan<<<1, 256, 0, stream>>>(bhist, boff, cur);
    k_part<<<PART_BLOCKS, 256, 0, stream>>>(srcp, dstp, cur, packed);

    // ---- layer 1 ----
    hipMemsetAsync(bnsum, 0, 128*sizeof(float), stream);
    k_bagg<true><<<NB, 256, 0, stream>>>(x, packed, boff, bufA, deg);
    k_gemm<false><<<1024, 256, 0, stream>>>(bufA, x, deg, Wl0, bl0, Wr0,
                                            nullptr, nullptr, bnsum, bnsq);
    k_bnfin<<<1, 64, 0, stream>>>(bnsum, bnsq, g0, b0, scale0, shift0);

    // ---- layer 2 ----
    hipMemsetAsync(bnsum, 0, 128*sizeof(float), stream);
    k_bagg<false><<<NB, 256, 0, stream>>>(bufA, packed, boff, bufB, deg);
    k_gemm<true><<<1024, 256, 0, stream>>>(bufB, bufA, deg, Wl1, bl1, Wr1,
                                           scale0, shift0, bnsum, bnsq);
    k_bnfin<<<1, 64, 0, stream>>>(bnsum, bnsq, g1, b1, scale1, shift1);

    // ---- pooling + MLP ----
    k_pool2<<<N_GRAPHS, 256, 0, stream>>>(bufB, batch, scale1, shift1, pooled);
    k_mlp<<<N_GRAPHS, 256, 0, stream>>>(pooled, gf, Wm0, bm0, Wm1, bm1, Wm2, bm2, (float*)d_out);
}

// Round 5
// 446.151 us; speedup vs baseline: 3.7452x; 3.7452x over previous
//
#include <hip/hip_runtime.h>

#define N_NODES 100000
#define N_EDGES 1600000
#define N_GRAPHS 128
#define FDIM 64
#define EPSV 1e-5f
#define NEG 0.01f

#define NB 782              // ceil(N_NODES/128) dst-range buckets
#define PART_BLOCKS 391     // ceil(N_EDGES/4096)

__device__ __forceinline__ float leaky(float x){ return x >= 0.f ? x : NEG*x; }
__device__ __forceinline__ float bcastf(float v, int k){
    return __uint_as_float((unsigned)__builtin_amdgcn_readlane(__float_as_uint(v), k));
}

// ================= bucket histogram (782 bins, LDS-reduced) =================
__global__ __launch_bounds__(256) void k_bh(const int* __restrict__ dst, int* __restrict__ bhist){
    __shared__ int lh[NB];
    int t = threadIdx.x;
    for (int i = t; i < NB; i += 256) lh[i] = 0;
    __syncthreads();
    int base = blockIdx.x * 4096;
    #pragma unroll
    for (int k = 0; k < 16; ++k){
        int e = base + k*256 + t;
        if (e < N_EDGES) atomicAdd(&lh[dst[e] >> 7], 1);
    }
    __syncthreads();
    for (int i = t; i < NB; i += 256) if (lh[i]) atomicAdd(&bhist[i], lh[i]);
}

// ================= single-block exclusive scan of NB bucket sizes =================
__global__ __launch_bounds__(256) void k_bscan(const int* __restrict__ bhist,
                                               int* __restrict__ boff, int* __restrict__ cur){
    __shared__ int lds[256];
    int t = threadIdx.x;
    int base = t*4;
    int v0 = (base+0 < NB) ? bhist[base+0] : 0;
    int v1 = (base+1 < NB) ? bhist[base+1] : 0;
    int v2 = (base+2 < NB) ? bhist[base+2] : 0;
    int v3 = (base+3 < NB) ? bhist[base+3] : 0;
    lds[t] = v0+v1+v2+v3; __syncthreads();
    for (int off = 1; off < 256; off <<= 1){
        int add = (t >= off) ? lds[t-off] : 0; __syncthreads();
        lds[t] += add; __syncthreads();
    }
    int excl = (t > 0) ? lds[t-1] : 0;
    int p0 = excl, p1 = excl+v0, p2 = excl+v0+v1, p3 = excl+v0+v1+v2;
    if (base+0 < NB){ boff[base+0] = p0; cur[base+0] = p0; }
    if (base+1 < NB){ boff[base+1] = p1; cur[base+1] = p1; }
    if (base+2 < NB){ boff[base+2] = p2; cur[base+2] = p2; }
    if (base+3 < NB){ boff[base+3] = p3; cur[base+3] = p3; }
    if (t == 0) boff[NB] = N_EDGES;
}

// ================= partition edges into dst buckets, packed (src<<7)|dst_local =================
__global__ __launch_bounds__(256) void k_part(const int* __restrict__ src, const int* __restrict__ dst,
                                              int* __restrict__ cur, int* __restrict__ packed){
    __shared__ int lh[NB];
    __shared__ int lc[NB];
    int t = threadIdx.x;
    for (int i = t; i < NB; i += 256) lh[i] = 0;
    __syncthreads();
    int base = blockIdx.x * 4096;
    int d[16];
    #pragma unroll
    for (int k = 0; k < 16; ++k){
        int e = base + k*256 + t;
        d[k] = (e < N_EDGES) ? dst[e] : -1;
        if (d[k] >= 0) atomicAdd(&lh[d[k] >> 7], 1);
    }
    __syncthreads();
    for (int i = t; i < NB; i += 256) lc[i] = atomicAdd(&cur[i], lh[i]);
    __syncthreads();
    #pragma unroll
    for (int k = 0; k < 16; ++k){
        int e = base + k*256 + t;
        if (e < N_EDGES){
            int b = d[k] >> 7;
            int p = atomicAdd(&lc[b], 1);
            packed[p] = (src[e] << 7) | (d[k] & 127);
        }
    }
}

// ======== per-bucket counting sort: packed bucket -> CSR (rs + col), coalesced region ========
__global__ __launch_bounds__(256) void k_sort(const int* __restrict__ packed,
                                              const int* __restrict__ boff,
                                              int* __restrict__ rs, int* __restrict__ col){
    __shared__ int hist[128];
    __shared__ int curs[128];
    int b = blockIdx.x, t = threadIdx.x;
    int e0 = boff[b], e1 = boff[b+1];
    if (t < 128) hist[t] = 0;
    __syncthreads();
    for (int e = e0 + t; e < e1; e += 256)
        atomicAdd(&hist[packed[e] & 127], 1);
    __syncthreads();
    int cnt = (t < 128) ? hist[t] : 0;
    __syncthreads();
    for (int off = 1; off < 128; off <<= 1){
        int add = (t < 128 && t >= off) ? hist[t-off] : 0;
        __syncthreads();
        if (t < 128) hist[t] += add;
        __syncthreads();
    }
    int nbase = b << 7;
    int nloc = min(128, N_NODES - nbase);
    if (t < nloc){
        int excl = hist[t] - cnt;          // exclusive scan
        rs[nbase + t] = e0 + excl;
        curs[t] = excl;
    }
    __syncthreads();
    for (int e = e0 + t; e < e1; e += 256){
        int v = packed[e];
        int p = atomicAdd(&curs[v & 127], 1);
        col[e0 + p] = ((unsigned)v) >> 7;
    }
    if (b == 0 && t == 0) rs[N_NODES] = N_EDGES;
}

// ============ pure gather-mean: wave per node, 16 lanes x float4, 4 edges/instr ============
__global__ __launch_bounds__(256) void k_agg(
    const float* __restrict__ xin, const int* __restrict__ rs, const int* __restrict__ col,
    float* __restrict__ agg)
{
    int t = threadIdx.x;
    int lane = t & 63;
    int sub = lane >> 4;          // edge slot 0..3
    int q   = lane & 15;          // feature quad
    int wid = (blockIdx.x << 2) + (t >> 6);
    const int nw = gridDim.x << 2;
    for (int n = wid; n < N_NODES; n += nw){
        int e0 = __builtin_amdgcn_readfirstlane(rs[n]);
        int e1 = __builtin_amdgcn_readfirstlane(rs[n+1]);
        float ax=0.f, ay=0.f, az=0.f, aw=0.f;
        for (int e = e0; e < e1; e += 8){
            int i0 = e + sub, i1 = e + 4 + sub;
            if (i0 < e1){
                const float4* row = (const float4*)(xin + ((size_t)col[i0] << 6));
                float4 v = row[q];
                ax += v.x; ay += v.y; az += v.z; aw += v.w;
            }
            if (i1 < e1){
                const float4* row = (const float4*)(xin + ((size_t)col[i1] << 6));
                float4 v = row[q];
                ax += v.x; ay += v.y; az += v.z; aw += v.w;
            }
        }
        ax += __shfl_xor(ax, 16, 64); ay += __shfl_xor(ay, 16, 64);
        az += __shfl_xor(az, 16, 64); aw += __shfl_xor(aw, 16, 64);
        ax += __shfl_xor(ax, 32, 64); ay += __shfl_xor(ay, 32, 64);
        az += __shfl_xor(az, 32, 64); aw += __shfl_xor(aw, 32, 64);
        if (sub == 0){
            float rd = 1.f / fmaxf((float)(e1 - e0), 1.f);
            float4 o = make_float4(ax*rd, ay*rd, az*rd, aw*rd);
            ((float4*)(agg + ((size_t)n << 6)))[q] = o;
        }
    }
}

// ============ streaming dual-GEMM + leaky + BN partials; affine folded into weights ============
template<bool AFF>
__global__ __launch_bounds__(256) void k_gemm(
    float* aggh, const float* __restrict__ xin,
    const int* __restrict__ rs,
    const float* __restrict__ Wl, const float* __restrict__ bl,
    const float* __restrict__ Wr,
    const float* __restrict__ scale, const float* __restrict__ shift,
    float* __restrict__ bnsum, float* __restrict__ bnsq)
{
    __shared__ float sWl[4096];
    __shared__ float sWr[4096];
    __shared__ float red[256];
    int t = threadIdx.x;
    int lane = t & 63;
    for (int i = t; i < 4096; i += 256){
        float s = AFF ? scale[i >> 6] : 1.f;
        sWl[i] = Wl[i] * s;
        sWr[i] = Wr[i] * s;
    }
    float bb = bl[lane], bd = 0.f;
    if (AFF){
        #pragma unroll 8
        for (int k = 0; k < 64; ++k){
            float sh = shift[k];
            bb += sh * Wr[(k<<6) + lane];
            bd += sh * Wl[(k<<6) + lane];
        }
    }
    __syncthreads();
    float bs = 0.f, bq = 0.f;
    int wid = (blockIdx.x << 2) + (t >> 6);
    int nw = gridDim.x << 2;
    for (int c = wid; c < N_NODES/4; c += nw){
        int n0 = c << 2;
        float aA[4], aX[4], acc[4];
        #pragma unroll
        for (int m = 0; m < 4; ++m){
            aA[m] = aggh[((size_t)(n0+m) << 6) + lane];
            aX[m] = xin[((size_t)(n0+m) << 6) + lane];
            if (AFF){
                int d = rs[n0+m+1] - rs[n0+m];
                acc[m] = bb + (d > 0 ? bd : 0.f);
            } else acc[m] = bb;
        }
        #pragma unroll 8
        for (int k = 0; k < 64; ++k){
            float wl = sWl[(k<<6) + lane];
            float wr = sWr[(k<<6) + lane];
            #pragma unroll
            for (int m = 0; m < 4; ++m)
                acc[m] += bcastf(aA[m], k)*wl + bcastf(aX[m], k)*wr;
        }
        #pragma unroll
        for (int m = 0; m < 4; ++m){
            float h = leaky(acc[m]);
            aggh[((size_t)(n0+m) << 6) + lane] = h;
            bs += h; bq += h*h;
        }
    }
    red[t] = bs; __syncthreads();
    if (t < 64) atomicAdd(&bnsum[t], red[t]+red[t+64]+red[t+128]+red[t+192]);
    __syncthreads();
    red[t] = bq; __syncthreads();
    if (t < 64) atomicAdd(&bnsq[t],  red[t]+red[t+64]+red[t+128]+red[t+192]);
}

// ============ BN finalize ============
__global__ void k_bnfin(const float* __restrict__ sum, const float* __restrict__ sumsq,
                        const float* __restrict__ gamma, const float* __restrict__ beta,
                        float* __restrict__ scale, float* __restrict__ shift){
    int j = threadIdx.x;
    if (j < FDIM){
        float mu  = sum[j]   * (1.0f/N_NODES);
        float var = sumsq[j] * (1.0f/N_NODES) - mu*mu;
        float sc  = gamma[j] * rsqrtf(var + EPSV);
        scale[j] = sc;
        shift[j] = beta[j] - mu*sc;
    }
}

// ============ pooling: sorted batch -> segmented reduction ============
__global__ __launch_bounds__(256) void k_pool2(
    const float* __restrict__ h, const int* __restrict__ batch,
    const float* __restrict__ scale, const float* __restrict__ shift,
    float* __restrict__ pooled)
{
    __shared__ int seg[2];
    __shared__ float red[256];
    int g = blockIdx.x, t = threadIdx.x, j = t & 63, slot = t >> 6;
    if (t < 2){
        int target = g + t;
        int lo = 0, hi = N_NODES;
        while (lo < hi){ int mid = (lo+hi)>>1; if (batch[mid] < target) lo = mid+1; else hi = mid; }
        seg[t] = lo;
    }
    __syncthreads();
    int start = seg[0], end = seg[1];
    float acc = 0.f;
    for (int n = start + slot; n < end; n += 4)
        acc += h[(long long)n*FDIM + j];
    red[t] = acc; __syncthreads();
    if (t < 64){
        float s = red[t]+red[t+64]+red[t+128]+red[t+192];
        float c = fmaxf((float)(end - start), 1.f);
        pooled[g*FDIM + t] = (end > start) ? (s/c)*scale[t] + shift[t] : 0.f;
    }
}

// ============ final MLP ============
__global__ __launch_bounds__(256) void k_mlp(
    const float* __restrict__ pooled, const float* __restrict__ gf,
    const float* __restrict__ Wm0, const float* __restrict__ bm0,
    const float* __restrict__ Wm1, const float* __restrict__ bm1,
    const float* __restrict__ Wm2, const float* __restrict__ bm2,
    float* __restrict__ out)
{
    __shared__ float z[128];
    __shared__ float h1[256];
    __shared__ float h2[128];
    int g = blockIdx.x, t = threadIdx.x;
    if (t < 64)       z[t] = pooled[g*FDIM + t];
    else if (t < 128) z[t] = gf[g*FDIM + (t-64)];
    __syncthreads();
    float acc = bm0[t];
    #pragma unroll 8
    for (int k = 0; k < 128; ++k) acc += z[k]*Wm0[k*256 + t];
    h1[t] = leaky(acc);
    __syncthreads();
    if (t < 128){
        float a = bm1[t];
        #pragma unroll 8
        for (int k = 0; k < 256; ++k) a += h1[k]*Wm1[k*128 + t];
        h2[t] = leaky(a);
    }
    __syncthreads();
    if (t < 2){
        float a = bm2[t];
        for (int k = 0; k < 128; ++k) a += h2[k]*Wm2[k*2 + t];
        out[g*2 + t] = a;
    }
}

extern "C" void kernel_launch(void* const* d_in, const int* in_sizes, int n_in,
                              void* d_out, int out_size, void* d_ws, size_t ws_size,
                              hipStream_t stream) {
    const float* x     = (const float*)d_in[0];
    const int*   ei    = (const int*)d_in[1];
    const float* gf    = (const float*)d_in[2];
    const int*   batch = (const int*)d_in[3];
    const float* Wl0 = (const float*)d_in[4];
    const float* bl0 = (const float*)d_in[5];
    const float* Wr0 = (const float*)d_in[6];
    const float* g0  = (const float*)d_in[7];
    const float* b0  = (const float*)d_in[8];
    const float* Wl1 = (const float*)d_in[9];
    const float* bl1 = (const float*)d_in[10];
    const float* Wr1 = (const float*)d_in[11];
    const float* g1  = (const float*)d_in[12];
    const float* b1  = (const float*)d_in[13];
    const float* Wm0 = (const float*)d_in[14];
    const float* bm0 = (const float*)d_in[15];
    const float* Wm1 = (const float*)d_in[16];
    const float* bm1 = (const float*)d_in[17];
    const float* Wm2 = (const float*)d_in[18];
    const float* bm2 = (const float*)d_in[19];

    // ---- workspace ----
    int*   bhist  = (int*)d_ws;                      // [NB]
    int*   boff   = bhist + NB;                      // [NB+1]
    int*   cur    = boff + NB + 1;                   // [NB]   (total 2347 -> pad 2348)
    int*   packed = (int*)d_ws + 2348;               // [E]
    int*   rs     = packed + N_EDGES;                // [N+1]  (pad to 100004)
    int*   col    = rs + 100004;                     // [E]
    float* bufA   = (float*)(col + N_EDGES);         // [N,64] agg1 -> h1 (in-place)
    float* bufB   = bufA + (size_t)N_NODES*FDIM;     // [N,64] agg2 -> h2 (in-place)
    float* bnsum  = bufB + (size_t)N_NODES*FDIM;     // [64]
    float* bnsq   = bnsum + 64;
    float* scale0 = bnsum + 128;
    float* shift0 = bnsum + 192;
    float* scale1 = bnsum + 256;
    float* shift1 = bnsum + 320;
    float* pooled = bnsum + 384;                     // [128,64]

    const int* srcp = ei;
    const int* dstp = ei + N_EDGES;

    // ---- bucketed CSR build ----
    hipMemsetAsync(bhist, 0, NB*sizeof(int), stream);
    k_bh<<<PART_BLOCKS, 256, 0, stream>>>(dstp, bhist);
    k_bscan<<<1, 256, 0, stream>>>(bhist, boff, cur);
    k_part<<<PART_BLOCKS, 256, 0, stream>>>(srcp, dstp, cur, packed);
    k_sort<<<NB, 256, 0, stream>>>(packed, boff, rs, col);

    // ---- layer 1 ----
    hipMemsetAsync(bnsum, 0, 128*sizeof(float), stream);
    k_agg<<<2048, 256, 0, stream>>>(x, rs, col, bufA);
    k_gemm<false><<<1024, 256, 0, stream>>>(bufA, x, rs, Wl0, bl0, Wr0,
                                            nullptr, nullptr, bnsum, bnsq);
    k_bnfin<<<1, 64, 0, stream>>>(bnsum, bnsq, g0, b0, scale0, shift0);

    // ---- layer 2 ----
    hipMemsetAsync(bnsum, 0, 128*sizeof(float), stream);
    k_agg<<<2048, 256, 0, stream>>>(bufA, rs, col, bufB);
    k_gemm<true><<<1024, 256, 0, stream>>>(bufB, bufA, rs, Wl1, bl1, Wr1,
                                           scale0, shift0, bnsum, bnsq);
    k_bnfin<<<1, 64, 0, stream>>>(bnsum, bnsq, g1, b1, scale1, shift1);

    // ---- pooling + MLP ----
    k_pool2<<<N_GRAPHS, 256, 0, stream>>>(bufB, batch, scale1, shift1, pooled);
    k_mlp<<<N_GRAPHS, 256, 0, stream>>>(pooled, gf, Wm0, bm0, Wm1, bm1, Wm2, bm2, (float*)d_out);
}